// Round 7
// baseline (749.528 us; speedup 1.0000x reference)
//
#include <hip/hip_runtime.h>
#include <math.h>

#define NB 4
#define NH 128
#define NW 128
#define TH 256
#define TW 256
#define AST 264          // act row stride in f16 elems (528 B)
#define K0 96            // layer0 K padded 84->96 (zeros)
#define MROWS 256        // rows per block = 64 px * 4 ensembles
#define PIXB 64          // pixels per block

typedef _Float16 f16;
typedef f16  f16x8 __attribute__((ext_vector_type(8)));
typedef f16  f16x4v __attribute__((ext_vector_type(4)));
typedef float f32x4 __attribute__((ext_vector_type(4)));

// ws layout (f16): W0t[256][96] | W1t[256][256] | W2t[256][256] | W3t[16][256] | ft[B][H][W][64]
#define OFF_W1 24576
#define OFF_W2 (OFF_W1 + 65536)
#define OFF_W3 (OFF_W2 + 65536)
#define WS_W_ELEMS (OFF_W3 + 4096)
#define FT_ELEMS (NB * NH * NW * 64)

__global__ void cvt_weights(const float* __restrict__ w0, const float* __restrict__ w1,
                            const float* __restrict__ w2, const float* __restrict__ w3,
                            f16* __restrict__ ws) {
  const int i = blockIdx.x * 256 + threadIdx.x;
  if (i < 24576) {                       // W0t[n][k] = w0[k][n], k<84 else 0
    const int n = i / 96, k = i - n * 96;
    ws[i] = (k < 84) ? (f16)w0[k * 256 + n] : (f16)0.f;
  } else if (i < OFF_W2) {               // W1t[n][k] = w1[k][n]
    const int j = i - OFF_W1; const int n = j >> 8, k = j & 255;
    ws[i] = (f16)w1[k * 256 + n];
  } else if (i < OFF_W3) {               // W2t
    const int j = i - OFF_W2; const int n = j >> 8, k = j & 255;
    ws[i] = (f16)w2[k * 256 + n];
  } else if (i < WS_W_ELEMS) {           // W3t[n][k] = w3[k][n], n<3 else 0
    const int j = i - OFF_W3; const int n = j >> 8, k = j & 255;
    ws[i] = (n < 3) ? (f16)w3[k * 3 + n] : (f16)0.f;
  }
}

// feat f32 [B][64][H][W] -> ft f16 [B][H][W][64]; coalesced both sides via LDS tile.
__global__ void transpose_feat(const float* __restrict__ feat, f16* __restrict__ ft) {
  __shared__ f16 tile[64][66];
  const int bid = blockIdx.x;                 // 4*128*2 = 1024 blocks
  const int xt = bid & 1, y = (bid >> 1) & 127, b = bid >> 8;
  const int x0 = xt * 64;
  {
    const int c4 = threadIdx.x >> 6, x = threadIdx.x & 63;
#pragma unroll
    for (int co = 0; co < 16; ++co) {
      const int c = co * 4 + c4;
      tile[x][c] = (f16)feat[((size_t)(b * 64 + c) * NH + y) * NW + x0 + x];
    }
  }
  __syncthreads();
  {
    const int x4 = threadIdx.x >> 6, c = threadIdx.x & 63;
#pragma unroll
    for (int xo = 0; xo < 16; ++xo) {
      const int x = xo * 4 + x4;
      ft[((size_t)(b * NH + y) * NW + x0 + x) * 64 + c] = tile[x][c];
    }
  }
}

// One 256-wide layer on matrix cores, IN-PLACE on a single LDS act buffer.
// 16 waves as 4x4 grid: wave (wm,wn) -> tile M=64 (rows wm*64..+63) x N=64
// (cols wn*64..+63). A = weights (global, L2-hot, dbuf). B = act (LDS).
// All reads complete -> barrier -> relu+cvt epilogue writes same buffer.
// Caller must barrier after return.
template<int K>
__device__ __forceinline__ void dense_layer(const f16* __restrict__ Wt,
                                            const float* __restrict__ bias,
                                            f16* act, int wm, int wn, int l) {
  constexpr int NK = K / 32;
  const int nl = l & 15, kq = l >> 4;
  const f16* Abase = Wt + (size_t)(wn * 64 + nl) * K + kq * 8;
  const f16* Bbase = act + (wm * 64 + nl) * AST + kq * 8;

  f32x4 acc[4][4];
#pragma unroll
  for (int nf = 0; nf < 4; ++nf) {
    const float4 b4 = *(const float4*)(bias + wn * 64 + nf * 16 + kq * 4);
    f32x4 a; a[0] = b4.x; a[1] = b4.y; a[2] = b4.z; a[3] = b4.w;
#pragma unroll
    for (int mf = 0; mf < 4; ++mf) acc[nf][mf] = a;
  }

  f16x8 A0[4], A1[4], B[4];
#pragma unroll
  for (int nf = 0; nf < 4; ++nf) A0[nf] = *(const f16x8*)(Abase + nf * 16 * K);

#pragma unroll
  for (int ks = 0; ks < NK; ++ks) {
    f16x8* cur = (ks & 1) ? A1 : A0;
    f16x8* nxt = (ks & 1) ? A0 : A1;
    if (ks + 1 < NK) {
#pragma unroll
      for (int nf = 0; nf < 4; ++nf)
        nxt[nf] = *(const f16x8*)(Abase + (ks + 1) * 32 + nf * 16 * K);
    }
#pragma unroll
    for (int mf = 0; mf < 4; ++mf)
      B[mf] = *(const f16x8*)(Bbase + ks * 32 + mf * 16 * AST);
    __builtin_amdgcn_s_setprio(1);
#pragma unroll
    for (int nf = 0; nf < 4; ++nf)
#pragma unroll
      for (int mf = 0; mf < 4; ++mf)
        acc[nf][mf] = __builtin_amdgcn_mfma_f32_16x16x32_f16(cur[nf], B[mf], acc[nf][mf], 0, 0, 0);
    __builtin_amdgcn_s_setprio(0);
  }

  __syncthreads();   // all waves done READING act -> safe to overwrite

#pragma unroll
  for (int nf = 0; nf < 4; ++nf)
#pragma unroll
    for (int mf = 0; mf < 4; ++mf) {
      f16x4v o;
      o[0] = (f16)fmaxf(acc[nf][mf][0], 0.f);
      o[1] = (f16)fmaxf(acc[nf][mf][1], 0.f);
      o[2] = (f16)fmaxf(acc[nf][mf][2], 0.f);
      o[3] = (f16)fmaxf(acc[nf][mf][3], 0.f);
      *(f16x4v*)(act + (wm * 64 + mf * 16 + nl) * AST + wn * 64 + nf * 16 + kq * 4) = o;
    }
}

template<bool USE_FT>
__global__ __launch_bounds__(1024, 1) void inr2d_mfma(
    const float* __restrict__ feat, const f16* __restrict__ ft,
    const float* __restrict__ b0, const float* __restrict__ b1,
    const float* __restrict__ b2, const float* __restrict__ b3,
    const f16* __restrict__ ws, float* __restrict__ out)
{
  __shared__ f16 act[MROWS][AST];      // 132 KB
  __shared__ float area_s[MROWS];
  __shared__ float pred_s[MROWS][4];

  const int t = threadIdx.x;
  // XCD-chunked swizzle (4096 % 8 == 0 -> bijective)
  const int blk = ((blockIdx.x & 7) << 9) | (blockIdx.x >> 3);

  // ---------- phase 0: build 256 input rows (64 px x 4 ensembles), f16 ----------
  {
    const int r = t >> 2, sub = t & 3;     // 4 threads per row, 16 ch each
    const int pix = r >> 2, e = r & 3;
    const int gp = blk * PIXB + pix;
    const int b = gp >> 16, rem = gp & 65535;
    const int oy = rem >> 8, ox = rem & 255;

    const float cy = (2.0f * oy + 1.0f) / (float)TH - 1.0f;
    const float cx = (2.0f * ox + 1.0f) / (float)TW - 1.0f;
    const float vx = (e & 2) ? 1.0f : -1.0f;
    const float vy = (e & 1) ? 1.0f : -1.0f;
    const float rr = 1.0f / (float)NH;

    float c0 = fminf(fmaxf(cy + vx * rr + 1e-6f, -1.0f + 1e-6f), 1.0f - 1e-6f);
    float c1 = fminf(fmaxf(cx + vy * rr + 1e-6f, -1.0f + 1e-6f), 1.0f - 1e-6f);

    const float ix = (c1 + 1.0f) * 0.5f * (float)(NW - 1);
    const float iy = (c0 + 1.0f) * 0.5f * (float)(NH - 1);
    const float x0f = floorf(ix), y0f = floorf(iy);
    int x0 = (int)x0f; x0 = max(0, min(x0, NW - 1));
    int x1 = min(x0 + 1, NW - 1);
    int y0 = (int)y0f; y0 = max(0, min(y0, NH - 1));
    int y1 = min(y0 + 1, NH - 1);
    const float wx1 = ix - x0f, wx0 = 1.0f - wx1;
    const float wy1 = iy - y0f, wy0 = 1.0f - wy1;
    const float w00 = wy0 * wx0, w01 = wy0 * wx1, w10 = wy1 * wx0, w11 = wy1 * wx1;

    if (USE_FT) {
      const f16* fb = ft + (size_t)b * (NH * NW * 64);
      const f16* r00 = fb + (size_t)(y0 * NW + x0) * 64 + sub * 16;
      const f16* r01 = fb + (size_t)(y0 * NW + x1) * 64 + sub * 16;
      const f16* r10 = fb + (size_t)(y1 * NW + x0) * 64 + sub * 16;
      const f16* r11 = fb + (size_t)(y1 * NW + x1) * 64 + sub * 16;
#pragma unroll
      for (int h = 0; h < 2; ++h) {
        const f16x8 a00 = *(const f16x8*)(r00 + h * 8);
        const f16x8 a01 = *(const f16x8*)(r01 + h * 8);
        const f16x8 a10 = *(const f16x8*)(r10 + h * 8);
        const f16x8 a11 = *(const f16x8*)(r11 + h * 8);
#pragma unroll
        for (int i = 0; i < 8; ++i) {
          const float v = w00 * (float)a00[i] + w01 * (float)a01[i] +
                          w10 * (float)a10[i] + w11 * (float)a11[i];
          act[r][sub * 16 + h * 8 + i] = (f16)v;
        }
      }
    } else {
      const float* fb = feat + (size_t)b * 64 * NH * NW;
      const int i00 = y0 * NW + x0, i01 = y0 * NW + x1;
      const int i10 = y1 * NW + x0, i11 = y1 * NW + x1;
#pragma unroll
      for (int i = 0; i < 16; ++i) {
        const int c = sub * 16 + i;
        const float* fc = fb + (size_t)c * (NH * NW);
        const float v = w00 * fc[i00] + w01 * fc[i01] + w10 * fc[i10] + w11 * fc[i11];
        act[r][c] = (f16)v;
      }
    }
    if (sub == 0) {
      const float qy = -1.0f + 1.0f / NH + (2.0f / NH) * (wy0 * (float)y0 + wy1 * (float)y1);
      const float qx = -1.0f + 1.0f / NW + (2.0f / NW) * (wx0 * (float)x0 + wx1 * (float)x1);
      const float rely = (cy - qy) * (float)NH;
      const float relx = (cx - qx) * (float)NW;
      act[r][64] = (f16)rely;
      act[r][65] = (f16)relx;
#pragma unroll
      for (int ll = 0; ll < 4; ++ll) {
        const float f = (float)(1 << ll) * (float)M_PI;
        act[r][66 + ll] = (f16)sinf(cy * f);
        act[r][70 + ll] = (f16)cosf(cy * f);
        act[r][74 + ll] = (f16)sinf(cx * f);
        act[r][78 + ll] = (f16)cosf(cx * f);
      }
      act[r][82] = (f16)1.0f;   // rel_cell: 2/256*128 = 1.0
      act[r][83] = (f16)1.0f;
#pragma unroll
      for (int z = 84; z < K0; ++z) act[r][z] = (f16)0.f;  // K-pad
      area_s[r] = fabsf(rely * relx) + 1e-9f;
    }
  }
  __syncthreads();

  const int w = t >> 6, l = t & 63;
  const int wm = w >> 2, wn = w & 3;   // wave tile: rows wm*64.., cols wn*64..

  dense_layer<K0 >(ws,          b0, &act[0][0], wm, wn, l);
  __syncthreads();
  dense_layer<256>(ws + OFF_W1, b1, &act[0][0], wm, wn, l);
  __syncthreads();
  dense_layer<256>(ws + OFF_W2, b2, &act[0][0], wm, wn, l);
  __syncthreads();

  // ---------- layer 3: 256 -> 3 (wave w handles rows w*16 .. w*16+15) ----------
  {
    const int nl = l & 15, kq = l >> 4;
    const f16* Abase = ws + OFF_W3 + nl * 256 + kq * 8;
    const f16* Bbase = &act[w * 16 + nl][0] + kq * 8;
    f32x4 acc = {0.f, 0.f, 0.f, 0.f};
#pragma unroll
    for (int ks = 0; ks < 8; ++ks) {
      f16x8 a = *(const f16x8*)(Abase + ks * 32);
      f16x8 b = *(const f16x8*)(Bbase + ks * 32);
      acc = __builtin_amdgcn_mfma_f32_16x16x32_f16(a, b, acc, 0, 0, 0);
    }
    if (l < 16) {
      float4 pr;
      pr.x = acc[0] + b3[0]; pr.y = acc[1] + b3[1]; pr.z = acc[2] + b3[2]; pr.w = 0.f;
      *(float4*)(&pred_s[w * 16 + l][0]) = pr;
    }
  }
  __syncthreads();

  // ---------- ensemble combine: pred_e weighted by area[3-e]/tot ----------
  if (t < PIXB * 3) {
    const int pix = t / 3, o = t - pix * 3;
    const int gp = blk * PIXB + pix;
    const int b = gp >> 16, rem = gp & 65535;
    const int oy = rem >> 8, ox = rem & 255;
    const int r0 = pix * 4;
    const float a0 = area_s[r0], a1 = area_s[r0 + 1], a2 = area_s[r0 + 2], a3 = area_s[r0 + 3];
    const float tot = a0 + a1 + a2 + a3;
    const float v = pred_s[r0][o] * a3 + pred_s[r0 + 1][o] * a2 +
                    pred_s[r0 + 2][o] * a1 + pred_s[r0 + 3][o] * a0;
    out[(((size_t)b * 3 + o) << 16) + (oy << 8) + ox] = v / tot;
  }
}

extern "C" void kernel_launch(void* const* d_in, const int* in_sizes, int n_in,
                              void* d_out, int out_size, void* d_ws, size_t ws_size,
                              hipStream_t stream) {
  const float* feat = (const float*)d_in[0];
  const float* w0 = (const float*)d_in[1];
  const float* b0 = (const float*)d_in[2];
  const float* w1 = (const float*)d_in[3];
  const float* b1 = (const float*)d_in[4];
  const float* w2 = (const float*)d_in[5];
  const float* b2 = (const float*)d_in[6];
  const float* w3 = (const float*)d_in[7];
  const float* b3 = (const float*)d_in[8];
  float* out = (float*)d_out;
  f16* ws = (f16*)d_ws;

  cvt_weights<<<(WS_W_ELEMS + 255) / 256, 256, 0, stream>>>(w0, w1, w2, w3, ws);

  const int blocks = (NB * TH * TW) / PIXB;  // 4096
  const bool use_ft = ws_size >= (size_t)(WS_W_ELEMS + FT_ELEMS) * sizeof(f16);
  if (use_ft) {
    f16* ft = ws + WS_W_ELEMS;
    transpose_feat<<<NB * NH * (NW / 64), 256, 0, stream>>>(feat, ft);
    inr2d_mfma<true><<<blocks, 1024, 0, stream>>>(feat, ft, b0, b1, b2, b3, ws, out);
  } else {
    inr2d_mfma<false><<<blocks, 1024, 0, stream>>>(feat, nullptr, b0, b1, b2, b3, ws, out);
  }
}

// Round 8
// 440.673 us; speedup vs baseline: 1.7009x; 1.7009x over previous
//
#include <hip/hip_runtime.h>
#include <math.h>

#define NB 4
#define NH 128
#define NW 128
#define TH 256
#define TW 256
#define AST 264          // act row stride in f16 elems (528 B, 16B-aligned rows)
#define K0 96            // layer0 K padded 84->96 (zeros)
#define MROWS 256        // rows per block = 64 px * 4 ensembles
#define PIXB 64          // pixels per block

typedef _Float16 f16;
typedef f16  f16x8 __attribute__((ext_vector_type(8)));
typedef f16  f16x4v __attribute__((ext_vector_type(4)));
typedef float f32x4 __attribute__((ext_vector_type(4)));
typedef float f32x16 __attribute__((ext_vector_type(16)));

// ws layout (f16): W0t[256][96] | W1t[256][256] | W2t[256][256] | W3t[16][256] |
//                  peY[256][8] | peX[256][8] | ft[B][H][W][64]
#define OFF_W1 24576
#define OFF_W2 (OFF_W1 + 65536)
#define OFF_W3 (OFF_W2 + 65536)
#define OFF_PE (OFF_W3 + 4096)
#define WS_W_ELEMS (OFF_PE + 4096)
#define FT_ELEMS (NB * NH * NW * 64)

__global__ void cvt_weights(const float* __restrict__ w0, const float* __restrict__ w1,
                            const float* __restrict__ w2, const float* __restrict__ w3,
                            f16* __restrict__ ws) {
  const int i = blockIdx.x * 256 + threadIdx.x;
  if (i < 24576) {                       // W0t[n][k] = w0[k][n], k<84 else 0
    const int n = i / 96, k = i - n * 96;
    ws[i] = (k < 84) ? (f16)w0[k * 256 + n] : (f16)0.f;
  } else if (i < OFF_W2) {               // W1t[n][k] = w1[k][n]
    const int j = i - OFF_W1; const int n = j >> 8, k = j & 255;
    ws[i] = (f16)w1[k * 256 + n];
  } else if (i < OFF_W3) {               // W2t
    const int j = i - OFF_W2; const int n = j >> 8, k = j & 255;
    ws[i] = (f16)w2[k * 256 + n];
  } else if (i < OFF_PE) {               // W3t[n][k] = w3[k][n], n<3 else 0
    const int j = i - OFF_W3; const int n = j >> 8, k = j & 255;
    ws[i] = (n < 3) ? (f16)w3[k * 3 + n] : (f16)0.f;
  } else if (i < WS_W_ELEMS) {           // pos-enc tables
    const int j = i - OFF_PE;            // [0,2048): peY, [2048,4096): peX
    const int o = (j & 2047) >> 3, e = j & 7;
    const float c = (2.0f * o + 1.0f) / 256.0f - 1.0f;
    const float f = (float)(1 << (e & 3)) * (float)M_PI;
    ws[i] = (f16)((e < 4) ? sinf(c * f) : cosf(c * f));
  }
}

// feat f32 [B][64][H][W] -> ft f16 [B][H][W][64]; coalesced both sides via LDS tile.
__global__ void transpose_feat(const float* __restrict__ feat, f16* __restrict__ ft) {
  __shared__ f16 tile[64][66];
  const int bid = blockIdx.x;                 // 4*128*2 = 1024 blocks
  const int xt = bid & 1, y = (bid >> 1) & 127, b = bid >> 8;
  const int x0 = xt * 64;
  {
    const int c4 = threadIdx.x >> 6, x = threadIdx.x & 63;
#pragma unroll
    for (int co = 0; co < 16; ++co) {
      const int c = co * 4 + c4;
      tile[x][c] = (f16)feat[((size_t)(b * 64 + c) * NH + y) * NW + x0 + x];
    }
  }
  __syncthreads();
  {
    const int x4 = threadIdx.x >> 6, c = threadIdx.x & 63;
#pragma unroll
    for (int xo = 0; xo < 16; ++xo) {
      const int x = xo * 4 + x4;
      ft[((size_t)(b * NH + y) * NW + x0 + x) * 64 + c] = tile[x][c];
    }
  }
}

// One 256-wide layer on matrix cores (32x32x16 frags), IN-PLACE on LDS act.
// 8 waves as 2x4: wave (wm,wn) -> tile M=128 (rows wm*128..) x N=64 (cols wn*64..).
// acc[2][4] f32x16 = 128 AGPR. A (weights, global/L2) and B (act, LDS) both
// depth-2 register-prefetched; fully unrolled so buffer indices are static.
// All reads done -> barrier -> relu+cvt epilogue writes same buffer.
// Caller must barrier after return.
template<int K>
__device__ __forceinline__ void dense_layer(const f16* __restrict__ Wt,
                                            const float* __restrict__ bias,
                                            f16* act, int wm, int wn, int l) {
  constexpr int NK = K / 16;           // K16 steps
  const int lo = l & 31, hi = l >> 5;
  const f16* Abase = Wt + (size_t)(wn * 64 + lo) * K + hi * 8;
  const f16* Bbase = act + (wm * 128 + lo) * AST + hi * 8;

  f32x16 acc[2][4];
#pragma unroll
  for (int nt = 0; nt < 2; ++nt) {
    f32x16 ci;
#pragma unroll
    for (int g = 0; g < 4; ++g) {
      const float4 b4 = *(const float4*)(bias + wn * 64 + nt * 32 + 8 * g + 4 * hi);
      ci[4 * g + 0] = b4.x; ci[4 * g + 1] = b4.y; ci[4 * g + 2] = b4.z; ci[4 * g + 3] = b4.w;
    }
#pragma unroll
    for (int mt = 0; mt < 4; ++mt) acc[nt][mt] = ci;
  }

  f16x8 Ab[3][2], Bb[3][4];
#pragma unroll
  for (int p = 0; p < 2; ++p) {        // prologue: ks = 0,1
#pragma unroll
    for (int nt = 0; nt < 2; ++nt) Ab[p][nt] = *(const f16x8*)(Abase + nt * 32 * K + p * 16);
#pragma unroll
    for (int mt = 0; mt < 4; ++mt) Bb[p][mt] = *(const f16x8*)(Bbase + mt * 32 * AST + p * 16);
  }

#pragma unroll
  for (int ks = 0; ks < NK; ++ks) {
    if (ks + 2 < NK) {
      const int d = (ks + 2) % 3;
#pragma unroll
      for (int nt = 0; nt < 2; ++nt) Ab[d][nt] = *(const f16x8*)(Abase + nt * 32 * K + (ks + 2) * 16);
#pragma unroll
      for (int mt = 0; mt < 4; ++mt) Bb[d][mt] = *(const f16x8*)(Bbase + mt * 32 * AST + (ks + 2) * 16);
    }
    const int c = ks % 3;
#pragma unroll
    for (int mt = 0; mt < 4; ++mt)
#pragma unroll
      for (int nt = 0; nt < 2; ++nt)
        acc[nt][mt] = __builtin_amdgcn_mfma_f32_32x32x16_f16(Ab[c][nt], Bb[c][mt], acc[nt][mt], 0, 0, 0);
  }

  __syncthreads();   // all waves done READING act -> safe to overwrite

#pragma unroll
  for (int nt = 0; nt < 2; ++nt)
#pragma unroll
    for (int mt = 0; mt < 4; ++mt)
#pragma unroll
      for (int g = 0; g < 4; ++g) {
        f16x4v o;
        o[0] = (f16)fmaxf(acc[nt][mt][4 * g + 0], 0.f);
        o[1] = (f16)fmaxf(acc[nt][mt][4 * g + 1], 0.f);
        o[2] = (f16)fmaxf(acc[nt][mt][4 * g + 2], 0.f);
        o[3] = (f16)fmaxf(acc[nt][mt][4 * g + 3], 0.f);
        *(f16x4v*)(act + (size_t)(wm * 128 + mt * 32 + lo) * AST +
                   wn * 64 + nt * 32 + 8 * g + 4 * hi) = o;
      }
}

template<bool USE_FT>
__global__ __launch_bounds__(512, 2) void inr2d_mfma(
    const float* __restrict__ feat, const f16* __restrict__ ft,
    const float* __restrict__ b0, const float* __restrict__ b1,
    const float* __restrict__ b2, const float* __restrict__ b3,
    const f16* __restrict__ ws, float* __restrict__ out)
{
  __shared__ f16 act[MROWS][AST];      // 132 KB
  __shared__ float area_s[MROWS];
  __shared__ float pred_s[MROWS][4];

  const int t = threadIdx.x;
  // XCD-chunked swizzle (4096 % 8 == 0 -> bijective)
  const int blk = ((blockIdx.x & 7) << 9) | (blockIdx.x >> 3);

  // ---------- phase 0: build 256 input rows (64 px x 4 ensembles), f16 ----------
  {
    const int r = t >> 1, sub = t & 1;     // 2 threads per row, 32 ch each
    const int pix = r >> 2, e = r & 3;
    const int gp = blk * PIXB + pix;
    const int b = gp >> 16, rem = gp & 65535;
    const int oy = rem >> 8, ox = rem & 255;

    const float cy = (2.0f * oy + 1.0f) / (float)TH - 1.0f;
    const float cx = (2.0f * ox + 1.0f) / (float)TW - 1.0f;
    const float vx = (e & 2) ? 1.0f : -1.0f;
    const float vy = (e & 1) ? 1.0f : -1.0f;
    const float rr = 1.0f / (float)NH;

    float c0 = fminf(fmaxf(cy + vx * rr + 1e-6f, -1.0f + 1e-6f), 1.0f - 1e-6f);
    float c1 = fminf(fmaxf(cx + vy * rr + 1e-6f, -1.0f + 1e-6f), 1.0f - 1e-6f);

    const float ix = (c1 + 1.0f) * 0.5f * (float)(NW - 1);
    const float iy = (c0 + 1.0f) * 0.5f * (float)(NH - 1);
    const float x0f = floorf(ix), y0f = floorf(iy);
    int x0 = (int)x0f; x0 = max(0, min(x0, NW - 1));
    int x1 = min(x0 + 1, NW - 1);
    int y0 = (int)y0f; y0 = max(0, min(y0, NH - 1));
    int y1 = min(y0 + 1, NH - 1);
    const float wx1 = ix - x0f, wx0 = 1.0f - wx1;
    const float wy1 = iy - y0f, wy0 = 1.0f - wy1;
    const float w00 = wy0 * wx0, w01 = wy0 * wx1, w10 = wy1 * wx0, w11 = wy1 * wx1;

    if (USE_FT) {
      const f16* fb = ft + (size_t)b * (NH * NW * 64);
      const f16* r00 = fb + (size_t)(y0 * NW + x0) * 64 + sub * 32;
      const f16* r01 = fb + (size_t)(y0 * NW + x1) * 64 + sub * 32;
      const f16* r10 = fb + (size_t)(y1 * NW + x0) * 64 + sub * 32;
      const f16* r11 = fb + (size_t)(y1 * NW + x1) * 64 + sub * 32;
#pragma unroll
      for (int h = 0; h < 4; ++h) {
        const f16x8 a00 = *(const f16x8*)(r00 + h * 8);
        const f16x8 a01 = *(const f16x8*)(r01 + h * 8);
        const f16x8 a10 = *(const f16x8*)(r10 + h * 8);
        const f16x8 a11 = *(const f16x8*)(r11 + h * 8);
#pragma unroll
        for (int i = 0; i < 8; ++i) {
          const float v = w00 * (float)a00[i] + w01 * (float)a01[i] +
                          w10 * (float)a10[i] + w11 * (float)a11[i];
          act[r][sub * 32 + h * 8 + i] = (f16)v;
        }
      }
    } else {
      const float* fb = feat + (size_t)b * 64 * NH * NW;
      const int i00 = y0 * NW + x0, i01 = y0 * NW + x1;
      const int i10 = y1 * NW + x0, i11 = y1 * NW + x1;
#pragma unroll
      for (int i = 0; i < 32; ++i) {
        const int c = sub * 32 + i;
        const float* fc = fb + (size_t)c * (NH * NW);
        const float v = w00 * fc[i00] + w01 * fc[i01] + w10 * fc[i10] + w11 * fc[i11];
        act[r][c] = (f16)v;
      }
    }
    if (sub == 0) {
      const float qy = -1.0f + 1.0f / NH + (2.0f / NH) * (wy0 * (float)y0 + wy1 * (float)y1);
      const float qx = -1.0f + 1.0f / NW + (2.0f / NW) * (wx0 * (float)x0 + wx1 * (float)x1);
      const float rely = (cy - qy) * (float)NH;
      const float relx = (cx - qx) * (float)NW;
      act[r][64] = (f16)rely;
      act[r][65] = (f16)relx;
      if (USE_FT) {
        const f16* py = ws + OFF_PE + (size_t)oy * 8;
        const f16* px = ws + OFF_PE + 2048 + (size_t)ox * 8;
#pragma unroll
        for (int j = 0; j < 8; ++j) { act[r][66 + j] = py[j]; act[r][74 + j] = px[j]; }
      } else {
#pragma unroll
        for (int ll = 0; ll < 4; ++ll) {
          const float f = (float)(1 << ll) * (float)M_PI;
          act[r][66 + ll] = (f16)sinf(cy * f);
          act[r][70 + ll] = (f16)cosf(cy * f);
          act[r][74 + ll] = (f16)sinf(cx * f);
          act[r][78 + ll] = (f16)cosf(cx * f);
        }
      }
      act[r][82] = (f16)1.0f;   // rel_cell: 2/256*128 = 1.0
      act[r][83] = (f16)1.0f;
#pragma unroll
      for (int z = 84; z < K0; ++z) act[r][z] = (f16)0.f;  // K-pad
      area_s[r] = fabsf(rely * relx) + 1e-9f;
    }
  }
  __syncthreads();

  const int w = t >> 6, l = t & 63;
  const int wm = w >> 2, wn = w & 3;   // wave tile: rows wm*128.., cols wn*64..

  dense_layer<K0 >(ws,          b0, &act[0][0], wm, wn, l);
  __syncthreads();
  dense_layer<256>(ws + OFF_W1, b1, &act[0][0], wm, wn, l);
  __syncthreads();
  dense_layer<256>(ws + OFF_W2, b2, &act[0][0], wm, wn, l);
  __syncthreads();

  // ---------- layer 3: 256 -> 3 (wave w handles rows w*32 .. w*32+31) ----------
  {
    const int nl = l & 15, kq = l >> 4;
    const f16* Abase = ws + OFF_W3 + nl * 256 + kq * 8;
#pragma unroll
    for (int p = 0; p < 2; ++p) {
      const f16* Bbase = &act[w * 32 + p * 16 + nl][0] + kq * 8;
      f32x4 acc = {0.f, 0.f, 0.f, 0.f};
#pragma unroll
      for (int ks = 0; ks < 8; ++ks) {
        f16x8 a = *(const f16x8*)(Abase + ks * 32);
        f16x8 b = *(const f16x8*)(Bbase + ks * 32);
        acc = __builtin_amdgcn_mfma_f32_16x16x32_f16(a, b, acc, 0, 0, 0);
      }
      if (l < 16) {
        float4 pr;
        pr.x = acc[0] + b3[0]; pr.y = acc[1] + b3[1]; pr.z = acc[2] + b3[2]; pr.w = 0.f;
        *(float4*)(&pred_s[w * 32 + p * 16 + l][0]) = pr;
      }
    }
  }
  __syncthreads();

  // ---------- ensemble combine: pred_e weighted by area[3-e]/tot ----------
  if (t < PIXB * 3) {
    const int pix = t / 3, o = t - pix * 3;
    const int gp = blk * PIXB + pix;
    const int b = gp >> 16, rem = gp & 65535;
    const int oy = rem >> 8, ox = rem & 255;
    const int r0 = pix * 4;
    const float a0 = area_s[r0], a1 = area_s[r0 + 1], a2 = area_s[r0 + 2], a3 = area_s[r0 + 3];
    const float tot = a0 + a1 + a2 + a3;
    const float v = pred_s[r0][o] * a3 + pred_s[r0 + 1][o] * a2 +
                    pred_s[r0 + 2][o] * a1 + pred_s[r0 + 3][o] * a0;
    out[(((size_t)b * 3 + o) << 16) + (oy << 8) + ox] = v / tot;
  }
}

extern "C" void kernel_launch(void* const* d_in, const int* in_sizes, int n_in,
                              void* d_out, int out_size, void* d_ws, size_t ws_size,
                              hipStream_t stream) {
  const float* feat = (const float*)d_in[0];
  const float* w0 = (const float*)d_in[1];
  const float* b0 = (const float*)d_in[2];
  const float* w1 = (const float*)d_in[3];
  const float* b1 = (const float*)d_in[4];
  const float* w2 = (const float*)d_in[5];
  const float* b2 = (const float*)d_in[6];
  const float* w3 = (const float*)d_in[7];
  const float* b3 = (const float*)d_in[8];
  float* out = (float*)d_out;
  f16* ws = (f16*)d_ws;

  cvt_weights<<<(WS_W_ELEMS + 255) / 256, 256, 0, stream>>>(w0, w1, w2, w3, ws);

  const int blocks = (NB * TH * TW) / PIXB;  // 4096
  const bool use_ft = ws_size >= (size_t)(WS_W_ELEMS + FT_ELEMS) * sizeof(f16);
  if (use_ft) {
    f16* ft = ws + WS_W_ELEMS;
    transpose_feat<<<NB * NH * (NW / 64), 256, 0, stream>>>(feat, ft);
    inr2d_mfma<true><<<blocks, 512, 0, stream>>>(feat, ft, b0, b1, b2, b3, ws, out);
  } else {
    inr2d_mfma<false><<<blocks, 512, 0, stream>>>(feat, nullptr, b0, b1, b2, b3, ws, out);
  }
}

// Round 9
// 437.520 us; speedup vs baseline: 1.7131x; 1.0072x over previous
//
#include <hip/hip_runtime.h>
#include <math.h>

#define NB 4
#define NH 128
#define NW 128
#define TH 256
#define TW 256
#define AST 264          // act row stride in f16 elems (528 B)
#define K0 96            // layer0 K padded 84->96 (zeros)
#define MROWS 256        // rows per block = 64 px * 4 ensembles
#define PIXB 64          // pixels per block

typedef _Float16 f16;
typedef f16  f16x8 __attribute__((ext_vector_type(8)));
typedef f16  f16x4v __attribute__((ext_vector_type(4)));
typedef float f32x4 __attribute__((ext_vector_type(4)));
typedef float f32x16 __attribute__((ext_vector_type(16)));

// ws layout (f16): W0t[256][96] | W1t[256][256] | W2t[256][256] | W3t[16][256] |
//                  peY[256][8] | peX[256][8] | ft[B][H][W][64]
#define OFF_W1 24576
#define OFF_W2 (OFF_W1 + 65536)
#define OFF_W3 (OFF_W2 + 65536)
#define OFF_PE (OFF_W3 + 4096)
#define WS_W_ELEMS (OFF_PE + 4096)
#define FT_ELEMS (NB * NH * NW * 64)

__device__ __forceinline__ void gload_lds16(const f16* g, f16* l) {
  // 16B per lane, dest = wave-uniform base + lane*16 (hardware rule)
  __builtin_amdgcn_global_load_lds(
      (const __attribute__((address_space(1))) void*)(g),
      (__attribute__((address_space(3))) void*)(l), 16, 0, 0);
}

__global__ void cvt_weights(const float* __restrict__ w0, const float* __restrict__ w1,
                            const float* __restrict__ w2, const float* __restrict__ w3,
                            f16* __restrict__ ws) {
  const int i = blockIdx.x * 256 + threadIdx.x;
  if (i < 24576) {                       // W0t[n][k] = w0[k][n], k<84 else 0
    const int n = i / 96, k = i - n * 96;
    ws[i] = (k < 84) ? (f16)w0[k * 256 + n] : (f16)0.f;
  } else if (i < OFF_W2) {               // W1t[n][k] = w1[k][n]
    const int j = i - OFF_W1; const int n = j >> 8, k = j & 255;
    ws[i] = (f16)w1[k * 256 + n];
  } else if (i < OFF_W3) {               // W2t
    const int j = i - OFF_W2; const int n = j >> 8, k = j & 255;
    ws[i] = (f16)w2[k * 256 + n];
  } else if (i < OFF_PE) {               // W3t[n][k] = w3[k][n], n<3 else 0
    const int j = i - OFF_W3; const int n = j >> 8, k = j & 255;
    ws[i] = (n < 3) ? (f16)w3[k * 3 + n] : (f16)0.f;
  } else if (i < WS_W_ELEMS) {           // pos-enc tables
    const int j = i - OFF_PE;            // [0,2048): peY, [2048,4096): peX
    const int o = (j & 2047) >> 3, e = j & 7;
    const float c = (2.0f * o + 1.0f) / 256.0f - 1.0f;
    const float f = (float)(1 << (e & 3)) * (float)M_PI;
    ws[i] = (f16)((e < 4) ? sinf(c * f) : cosf(c * f));
  }
}

// feat f32 [B][64][H][W] -> ft f16 [B][H][W][64]; coalesced both sides via LDS tile.
__global__ void transpose_feat(const float* __restrict__ feat, f16* __restrict__ ft) {
  __shared__ f16 tile[64][66];
  const int bid = blockIdx.x;                 // 4*128*2 = 1024 blocks
  const int xt = bid & 1, y = (bid >> 1) & 127, b = bid >> 8;
  const int x0 = xt * 64;
  {
    const int c4 = threadIdx.x >> 6, x = threadIdx.x & 63;
#pragma unroll
    for (int co = 0; co < 16; ++co) {
      const int c = co * 4 + c4;
      tile[x][c] = (f16)feat[((size_t)(b * 64 + c) * NH + y) * NW + x0 + x];
    }
  }
  __syncthreads();
  {
    const int x4 = threadIdx.x >> 6, c = threadIdx.x & 63;
#pragma unroll
    for (int xo = 0; xo < 16; ++xo) {
      const int x = xo * 4 + x4;
      ft[((size_t)(b * NH + y) * NW + x0 + x) * 64 + c] = tile[x][c];
    }
  }
}

// One 256-wide layer. W staged global->LDS via 3-deep ring (8 KB slices of K16),
// counted vmcnt(1) + one s_barrier per K-step (T3/T4). 8 waves as 2x4:
// wave (wm,wn) -> M=128 x N=64, acc[2][4] f32x16. In-place act epilogue.
// Caller must __syncthreads() after return.
// wlds ring layout per buffer: [half h][n][8 f16]  (h*2048 + n*8), 4096 f16/buf.
template<int K>
__device__ __forceinline__ void dense_layer(const f16* __restrict__ Wt,
                                            const float* __restrict__ bias,
                                            f16* act, f16* wlds,
                                            int wm, int wn, int l, int tid) {
  constexpr int NK = K / 16;
  const int lo = l & 31, hi = l >> 5;
  const int sn = tid & 255, sh = tid >> 8;
  const f16* src = Wt + (size_t)sn * K + sh * 8;       // this thread's 16B slot
  f16* wdst = wlds + (tid >> 6) * 512;                 // wave-uniform dest base
  const f16* Bbase = act + (wm * 128 + lo) * AST + hi * 8;

  f32x16 acc[2][4];
#pragma unroll
  for (int nt = 0; nt < 2; ++nt) {
    f32x16 ci;
#pragma unroll
    for (int g = 0; g < 4; ++g) {
      const float4 b4 = *(const float4*)(bias + wn * 64 + nt * 32 + 8 * g + 4 * hi);
      ci[4 * g + 0] = b4.x; ci[4 * g + 1] = b4.y; ci[4 * g + 2] = b4.z; ci[4 * g + 3] = b4.w;
    }
#pragma unroll
    for (int mt = 0; mt < 4; ++mt) acc[nt][mt] = ci;
  }

  // prologue: stage slices 0 and 1; ensure 0 landed everywhere
  gload_lds16(src + 0 * 16, wdst + 0 * 4096);
  gload_lds16(src + 1 * 16, wdst + 1 * 4096);
  asm volatile("s_waitcnt vmcnt(1)" ::: "memory");
  __builtin_amdgcn_s_barrier();

#pragma unroll
  for (int ks = 0; ks < NK; ++ks) {
    if (ks + 2 < NK)
      gload_lds16(src + (ks + 2) * 16, wdst + ((ks + 2) % 3) * 4096);

    const f16* wb = wlds + (ks % 3) * 4096 + hi * 2048;
    const f16x8 A0 = *(const f16x8*)(wb + (wn * 64 + 0 * 32 + lo) * 8);
    const f16x8 A1 = *(const f16x8*)(wb + (wn * 64 + 1 * 32 + lo) * 8);
    const f16x8 B0 = *(const f16x8*)(Bbase + 0 * 32 * AST + ks * 16);
    const f16x8 B1 = *(const f16x8*)(Bbase + 1 * 32 * AST + ks * 16);
    const f16x8 B2 = *(const f16x8*)(Bbase + 2 * 32 * AST + ks * 16);
    const f16x8 B3 = *(const f16x8*)(Bbase + 3 * 32 * AST + ks * 16);

    __builtin_amdgcn_s_setprio(1);
    acc[0][0] = __builtin_amdgcn_mfma_f32_32x32x16_f16(A0, B0, acc[0][0], 0, 0, 0);
    acc[0][1] = __builtin_amdgcn_mfma_f32_32x32x16_f16(A0, B1, acc[0][1], 0, 0, 0);
    acc[0][2] = __builtin_amdgcn_mfma_f32_32x32x16_f16(A0, B2, acc[0][2], 0, 0, 0);
    acc[0][3] = __builtin_amdgcn_mfma_f32_32x32x16_f16(A0, B3, acc[0][3], 0, 0, 0);
    acc[1][0] = __builtin_amdgcn_mfma_f32_32x32x16_f16(A1, B0, acc[1][0], 0, 0, 0);
    acc[1][1] = __builtin_amdgcn_mfma_f32_32x32x16_f16(A1, B1, acc[1][1], 0, 0, 0);
    acc[1][2] = __builtin_amdgcn_mfma_f32_32x32x16_f16(A1, B2, acc[1][2], 0, 0, 0);
    acc[1][3] = __builtin_amdgcn_mfma_f32_32x32x16_f16(A1, B3, acc[1][3], 0, 0, 0);
    __builtin_amdgcn_s_setprio(0);

    // stage(ks+1) must be globally complete before anyone enters step ks+1;
    // keep stage(ks+2) in flight across the barrier (counted vmcnt, never 0).
    asm volatile("s_waitcnt vmcnt(1)" ::: "memory");
    __builtin_amdgcn_s_barrier();
  }
  // all waves past final barrier => all act reads retired -> in-place write safe

#pragma unroll
  for (int nt = 0; nt < 2; ++nt)
#pragma unroll
    for (int mt = 0; mt < 4; ++mt)
#pragma unroll
      for (int g = 0; g < 4; ++g) {
        f16x4v o;
        o[0] = (f16)fmaxf(acc[nt][mt][4 * g + 0], 0.f);
        o[1] = (f16)fmaxf(acc[nt][mt][4 * g + 1], 0.f);
        o[2] = (f16)fmaxf(acc[nt][mt][4 * g + 2], 0.f);
        o[3] = (f16)fmaxf(acc[nt][mt][4 * g + 3], 0.f);
        *(f16x4v*)(act + (size_t)(wm * 128 + mt * 32 + lo) * AST +
                   wn * 64 + nt * 32 + 8 * g + 4 * hi) = o;
      }
}

template<bool USE_FT>
__global__ __launch_bounds__(512, 2) void inr2d_mfma(
    const float* __restrict__ feat, const f16* __restrict__ ft,
    const float* __restrict__ b0, const float* __restrict__ b1,
    const float* __restrict__ b2, const float* __restrict__ b3,
    const f16* __restrict__ ws, float* __restrict__ out)
{
  __shared__ f16 act[MROWS][AST];      // 132 KB
  __shared__ f16 wlds[3 * 4096];       // 24 KB W staging ring (3 x 8 KB)
  __shared__ float area_s[MROWS];      // 1 KB
  __shared__ f16 pred_s[MROWS][4];     // 2 KB   -> total 162,816 B

  const int t = threadIdx.x;
  // XCD-chunked swizzle (4096 % 8 == 0 -> bijective)
  const int blk = ((blockIdx.x & 7) << 9) | (blockIdx.x >> 3);

  // ---------- phase 0: build 256 input rows (64 px x 4 ensembles), f16 ----------
  {
    const int r = t >> 1, sub = t & 1;     // 2 threads per row, 32 ch each
    const int pix = r >> 2, e = r & 3;
    const int gp = blk * PIXB + pix;
    const int b = gp >> 16, rem = gp & 65535;
    const int oy = rem >> 8, ox = rem & 255;

    const float cy = (2.0f * oy + 1.0f) / (float)TH - 1.0f;
    const float cx = (2.0f * ox + 1.0f) / (float)TW - 1.0f;
    const float vx = (e & 2) ? 1.0f : -1.0f;
    const float vy = (e & 1) ? 1.0f : -1.0f;
    const float rr = 1.0f / (float)NH;

    float c0 = fminf(fmaxf(cy + vx * rr + 1e-6f, -1.0f + 1e-6f), 1.0f - 1e-6f);
    float c1 = fminf(fmaxf(cx + vy * rr + 1e-6f, -1.0f + 1e-6f), 1.0f - 1e-6f);

    const float ix = (c1 + 1.0f) * 0.5f * (float)(NW - 1);
    const float iy = (c0 + 1.0f) * 0.5f * (float)(NH - 1);
    const float x0f = floorf(ix), y0f = floorf(iy);
    int x0 = (int)x0f; x0 = max(0, min(x0, NW - 1));
    int x1 = min(x0 + 1, NW - 1);
    int y0 = (int)y0f; y0 = max(0, min(y0, NH - 1));
    int y1 = min(y0 + 1, NH - 1);
    const float wx1 = ix - x0f, wx0 = 1.0f - wx1;
    const float wy1 = iy - y0f, wy0 = 1.0f - wy1;
    const float w00 = wy0 * wx0, w01 = wy0 * wx1, w10 = wy1 * wx0, w11 = wy1 * wx1;

    if (USE_FT) {
      const f16* fb = ft + (size_t)b * (NH * NW * 64);
      const f16* r00 = fb + (size_t)(y0 * NW + x0) * 64 + sub * 32;
      const f16* r01 = fb + (size_t)(y0 * NW + x1) * 64 + sub * 32;
      const f16* r10 = fb + (size_t)(y1 * NW + x0) * 64 + sub * 32;
      const f16* r11 = fb + (size_t)(y1 * NW + x1) * 64 + sub * 32;
#pragma unroll
      for (int h = 0; h < 4; ++h) {
        const f16x8 a00 = *(const f16x8*)(r00 + h * 8);
        const f16x8 a01 = *(const f16x8*)(r01 + h * 8);
        const f16x8 a10 = *(const f16x8*)(r10 + h * 8);
        const f16x8 a11 = *(const f16x8*)(r11 + h * 8);
#pragma unroll
        for (int i = 0; i < 8; ++i) {
          const float v = w00 * (float)a00[i] + w01 * (float)a01[i] +
                          w10 * (float)a10[i] + w11 * (float)a11[i];
          act[r][sub * 32 + h * 8 + i] = (f16)v;
        }
      }
    } else {
      const float* fb = feat + (size_t)b * 64 * NH * NW;
      const int i00 = y0 * NW + x0, i01 = y0 * NW + x1;
      const int i10 = y1 * NW + x0, i11 = y1 * NW + x1;
#pragma unroll
      for (int i = 0; i < 32; ++i) {
        const int c = sub * 32 + i;
        const float* fc = fb + (size_t)c * (NH * NW);
        const float v = w00 * fc[i00] + w01 * fc[i01] + w10 * fc[i10] + w11 * fc[i11];
        act[r][c] = (f16)v;
      }
    }
    if (sub == 0) {
      const float qy = -1.0f + 1.0f / NH + (2.0f / NH) * (wy0 * (float)y0 + wy1 * (float)y1);
      const float qx = -1.0f + 1.0f / NW + (2.0f / NW) * (wx0 * (float)x0 + wx1 * (float)x1);
      const float rely = (cy - qy) * (float)NH;
      const float relx = (cx - qx) * (float)NW;
      act[r][64] = (f16)rely;
      act[r][65] = (f16)relx;
      if (USE_FT) {
        const f16* py = ws + OFF_PE + (size_t)oy * 8;
        const f16* px = ws + OFF_PE + 2048 + (size_t)ox * 8;
#pragma unroll
        for (int j = 0; j < 8; ++j) { act[r][66 + j] = py[j]; act[r][74 + j] = px[j]; }
      } else {
#pragma unroll
        for (int ll = 0; ll < 4; ++ll) {
          const float f = (float)(1 << ll) * (float)M_PI;
          act[r][66 + ll] = (f16)sinf(cy * f);
          act[r][70 + ll] = (f16)cosf(cy * f);
          act[r][74 + ll] = (f16)sinf(cx * f);
          act[r][78 + ll] = (f16)cosf(cx * f);
        }
      }
      act[r][82] = (f16)1.0f;   // rel_cell: 2/256*128 = 1.0
      act[r][83] = (f16)1.0f;
#pragma unroll
      for (int z = 84; z < K0; ++z) act[r][z] = (f16)0.f;  // K-pad
      area_s[r] = fabsf(rely * relx) + 1e-9f;
    }
  }
  __syncthreads();

  const int w = t >> 6, l = t & 63;
  const int wm = w >> 2, wn = w & 3;   // wave tile: rows wm*128.., cols wn*64..

  dense_layer<K0 >(ws,          b0, &act[0][0], wlds, wm, wn, l, t);
  __syncthreads();
  dense_layer<256>(ws + OFF_W1, b1, &act[0][0], wlds, wm, wn, l, t);
  __syncthreads();
  dense_layer<256>(ws + OFF_W2, b2, &act[0][0], wlds, wm, wn, l, t);
  __syncthreads();

  // ---------- layer 3: 256 -> 3 (wave w handles rows w*32 .. w*32+31) ----------
  {
    const int nl = l & 15, kq = l >> 4;
    const f16* Abase = ws + OFF_W3 + nl * 256 + kq * 8;
#pragma unroll
    for (int p = 0; p < 2; ++p) {
      const f16* Bbase2 = &act[w * 32 + p * 16 + nl][0] + kq * 8;
      f32x4 acc = {0.f, 0.f, 0.f, 0.f};
#pragma unroll
      for (int ks = 0; ks < 8; ++ks) {
        f16x8 a = *(const f16x8*)(Abase + ks * 32);
        f16x8 b = *(const f16x8*)(Bbase2 + ks * 32);
        acc = __builtin_amdgcn_mfma_f32_16x16x32_f16(a, b, acc, 0, 0, 0);
      }
      if (l < 16) {
        f16x4v pr;
        pr[0] = (f16)(acc[0] + b3[0]); pr[1] = (f16)(acc[1] + b3[1]);
        pr[2] = (f16)(acc[2] + b3[2]); pr[3] = (f16)0.f;
        *(f16x4v*)(&pred_s[w * 32 + p * 16 + l][0]) = pr;
      }
    }
  }
  __syncthreads();

  // ---------- ensemble combine: pred_e weighted by area[3-e]/tot ----------
  if (t < PIXB * 3) {
    const int pix = t / 3, o = t - pix * 3;
    const int gp = blk * PIXB + pix;
    const int b = gp >> 16, rem = gp & 65535;
    const int oy = rem >> 8, ox = rem & 255;
    const int r0 = pix * 4;
    const float a0 = area_s[r0], a1 = area_s[r0 + 1], a2 = area_s[r0 + 2], a3 = area_s[r0 + 3];
    const float tot = a0 + a1 + a2 + a3;
    const float v = (float)pred_s[r0][o] * a3 + (float)pred_s[r0 + 1][o] * a2 +
                    (float)pred_s[r0 + 2][o] * a1 + (float)pred_s[r0 + 3][o] * a0;
    out[(((size_t)b * 3 + o) << 16) + (oy << 8) + ox] = v / tot;
  }
}

extern "C" void kernel_launch(void* const* d_in, const int* in_sizes, int n_in,
                              void* d_out, int out_size, void* d_ws, size_t ws_size,
                              hipStream_t stream) {
  const float* feat = (const float*)d_in[0];
  const float* w0 = (const float*)d_in[1];
  const float* b0 = (const float*)d_in[2];
  const float* w1 = (const float*)d_in[3];
  const float* b1 = (const float*)d_in[4];
  const float* w2 = (const float*)d_in[5];
  const float* b2 = (const float*)d_in[6];
  const float* w3 = (const float*)d_in[7];
  const float* b3 = (const float*)d_in[8];
  float* out = (float*)d_out;
  f16* ws = (f16*)d_ws;

  cvt_weights<<<(WS_W_ELEMS + 255) / 256, 256, 0, stream>>>(w0, w1, w2, w3, ws);

  const int blocks = (NB * TH * TW) / PIXB;  // 4096
  const bool use_ft = ws_size >= (size_t)(WS_W_ELEMS + FT_ELEMS) * sizeof(f16);
  if (use_ft) {
    f16* ft = ws + WS_W_ELEMS;
    transpose_feat<<<NB * NH * (NW / 64), 256, 0, stream>>>(feat, ft);
    inr2d_mfma<true><<<blocks, 512, 0, stream>>>(feat, ft, b0, b1, b2, b3, ws, out);
  } else {
    inr2d_mfma<false><<<blocks, 512, 0, stream>>>(feat, nullptr, b0, b1, b2, b3, ws, out);
  }
}

// Round 11
// 434.428 us; speedup vs baseline: 1.7253x; 1.0071x over previous
//
#include <hip/hip_runtime.h>
#include <math.h>

#define NB 4
#define NH 128
#define NW 128
#define TH 256
#define TW 256
#define AST 264          // act row stride in f16 elems (528 B)
#define K0 96            // layer0 K padded 84->96 (zeros)
#define MROWS 256        // rows per block = 64 px * 4 ensembles
#define PIXB 64          // pixels per block

typedef _Float16 f16;
typedef f16  f16x8 __attribute__((ext_vector_type(8)));
typedef f16  f16x4v __attribute__((ext_vector_type(4)));
typedef float f32x4 __attribute__((ext_vector_type(4)));
typedef float f32x16 __attribute__((ext_vector_type(16)));

// ws layout (f16): W0t[256][96] | W1t[256][256] | W2t[256][256] | W3t[16][256] |
//                  peY[256][8] | peX[256][8] | ft[B][H][W][64]
#define OFF_W1 24576
#define OFF_W2 (OFF_W1 + 65536)
#define OFF_W3 (OFF_W2 + 65536)
#define OFF_PE (OFF_W3 + 4096)
#define WS_W_ELEMS (OFF_PE + 4096)
#define FT_ELEMS (NB * NH * NW * 64)

__device__ __forceinline__ void gload_lds16(const f16* g, f16* l) {
  // 16B per lane, dest = wave-uniform base + lane*16 (hardware rule)
  __builtin_amdgcn_global_load_lds(
      (const __attribute__((address_space(1))) void*)(g),
      (__attribute__((address_space(3))) void*)(l), 16, 0, 0);
}

__global__ void cvt_weights(const float* __restrict__ w0, const float* __restrict__ w1,
                            const float* __restrict__ w2, const float* __restrict__ w3,
                            f16* __restrict__ ws) {
  const int i = blockIdx.x * 256 + threadIdx.x;
  if (i < 24576) {                       // W0t[n][k] = w0[k][n], k<84 else 0
    const int n = i / 96, k = i - n * 96;
    ws[i] = (k < 84) ? (f16)w0[k * 256 + n] : (f16)0.f;
  } else if (i < OFF_W2) {               // W1t[n][k] = w1[k][n]
    const int j = i - OFF_W1; const int n = j >> 8, k = j & 255;
    ws[i] = (f16)w1[k * 256 + n];
  } else if (i < OFF_W3) {               // W2t
    const int j = i - OFF_W2; const int n = j >> 8, k = j & 255;
    ws[i] = (f16)w2[k * 256 + n];
  } else if (i < OFF_PE) {               // W3t[n][k] = w3[k][n], n<3 else 0
    const int j = i - OFF_W3; const int n = j >> 8, k = j & 255;
    ws[i] = (n < 3) ? (f16)w3[k * 3 + n] : (f16)0.f;
  } else if (i < WS_W_ELEMS) {           // pos-enc tables
    const int j = i - OFF_PE;            // [0,2048): peY, [2048,4096): peX
    const int o = (j & 2047) >> 3, e = j & 7;
    const float c = (2.0f * o + 1.0f) / 256.0f - 1.0f;
    const float f = (float)(1 << (e & 3)) * (float)M_PI;
    ws[i] = (f16)((e < 4) ? sinf(c * f) : cosf(c * f));
  }
}

// feat f32 [B][64][H][W] -> ft f16 [B][H][W][64]; coalesced both sides via LDS tile.
__global__ void transpose_feat(const float* __restrict__ feat, f16* __restrict__ ft) {
  __shared__ f16 tile[64][66];
  const int bid = blockIdx.x;                 // 4*128*2 = 1024 blocks
  const int xt = bid & 1, y = (bid >> 1) & 127, b = bid >> 8;
  const int x0 = xt * 64;
  {
    const int c4 = threadIdx.x >> 6, x = threadIdx.x & 63;
#pragma unroll
    for (int co = 0; co < 16; ++co) {
      const int c = co * 4 + c4;
      tile[x][c] = (f16)feat[((size_t)(b * 64 + c) * NH + y) * NW + x0 + x];
    }
  }
  __syncthreads();
  {
    const int x4 = threadIdx.x >> 6, c = threadIdx.x & 63;
#pragma unroll
    for (int xo = 0; xo < 16; ++xo) {
      const int x = xo * 4 + x4;
      ft[((size_t)(b * NH + y) * NW + x0 + x) * 64 + c] = tile[x][c];
    }
  }
}

// One 256-wide layer. Pipeline per K16-step ks (race-free version of R10):
//   1. gload stage(ks+2) -> ring buf (ks+2)%3      [issued at TOP of iter]
//   2. issue 6 ds_reads for frag(ks+1)             [buf staged+drained last iter]
//   3. lgkmcnt(6) -> frag(ks) ready; sched_barrier(0)
//   4. setprio(1); 8x MFMA 32x32x16; setprio(0)    [LDS serves frag(ks+1) under this]
//   5. vmcnt(0)  -> own stage(ks+2) drained        [~400cyc in flight, cheap]
//   6. s_barrier -> block-wide: stage(ks+2) visible to all next iter
// Cross-wave invariant W<=D-2 satisfied (D=2 ahead, 0 in flight across barrier).
// 8 waves as 2x4: wave (wm,wn) -> M=128 x N=64, acc[2][4] f32x16. In-place act.
template<int K>
__device__ __forceinline__ void dense_layer(const f16* __restrict__ Wt,
                                            const float* __restrict__ bias,
                                            f16* act, f16* wlds,
                                            int wm, int wn, int l, int tid) {
  constexpr int NK = K / 16;
  const int lo = l & 31, hi = l >> 5;
  const int sn = tid & 255, sh = tid >> 8;
  const f16* src = Wt + (size_t)sn * K + sh * 8;       // this thread's 16B slot
  f16* wdst = wlds + (tid >> 6) * 512;                 // wave-uniform dest base
  const f16* Bbase = act + (wm * 128 + lo) * AST + hi * 8;
  const int aoff = (wn * 64 + lo) * 8;                 // A-frag offset in [h] half

  f32x16 acc[2][4];
#pragma unroll
  for (int nt = 0; nt < 2; ++nt) {
    f32x16 ci;
#pragma unroll
    for (int g = 0; g < 4; ++g) {
      const float4 b4 = *(const float4*)(bias + wn * 64 + nt * 32 + 8 * g + 4 * hi);
      ci[4 * g + 0] = b4.x; ci[4 * g + 1] = b4.y; ci[4 * g + 2] = b4.z; ci[4 * g + 3] = b4.w;
    }
#pragma unroll
    for (int mt = 0; mt < 4; ++mt) acc[nt][mt] = ci;
  }

  // prologue: stage slices 0,1; drain BOTH (cross-wave: barrier follows)
  gload_lds16(src + 0 * 16, wdst + 0 * 4096);
  gload_lds16(src + 1 * 16, wdst + 1 * 4096);
  asm volatile("s_waitcnt vmcnt(0)" ::: "memory");
  __builtin_amdgcn_s_barrier();
  asm volatile("" ::: "memory");

  f16x8 Af[2][2], Bf[2][4];
  {  // frag(0) reads
    const f16* wb = wlds + hi * 2048 + aoff;
    Af[0][0] = *(const f16x8*)(wb);
    Af[0][1] = *(const f16x8*)(wb + 256);
    Bf[0][0] = *(const f16x8*)(Bbase + 0 * 32 * AST);
    Bf[0][1] = *(const f16x8*)(Bbase + 1 * 32 * AST);
    Bf[0][2] = *(const f16x8*)(Bbase + 2 * 32 * AST);
    Bf[0][3] = *(const f16x8*)(Bbase + 3 * 32 * AST);
  }

#pragma unroll
  for (int ks = 0; ks < NK; ++ks) {
    const int cur = ks & 1, nxt = cur ^ 1;
    // 1. stage(ks+2): buf (ks+2)%3 == (ks-1)%3, readers finished last iter
    if (ks + 2 < NK)
      gload_lds16(src + (ks + 2) * 16, wdst + ((ks + 2) % 3) * 4096);
    // 2. frag(ks+1) reads: staged by stage(ks+1), drained before last barrier
    if (ks + 1 < NK) {
      const f16* wb = wlds + ((ks + 1) % 3) * 4096 + hi * 2048 + aoff;
      Af[nxt][0] = *(const f16x8*)(wb);
      Af[nxt][1] = *(const f16x8*)(wb + 256);
      const f16* bb = Bbase + (ks + 1) * 16;
      Bf[nxt][0] = *(const f16x8*)(bb + 0 * 32 * AST);
      Bf[nxt][1] = *(const f16x8*)(bb + 1 * 32 * AST);
      Bf[nxt][2] = *(const f16x8*)(bb + 2 * 32 * AST);
      Bf[nxt][3] = *(const f16x8*)(bb + 3 * 32 * AST);
      asm volatile("s_waitcnt lgkmcnt(6)" ::: "memory");  // frag(ks) ready; 6 in flight
    } else {
      asm volatile("s_waitcnt lgkmcnt(0)" ::: "memory");
    }
    __builtin_amdgcn_sched_barrier(0);   // rule #18: keep MFMA below the waitcnt

    __builtin_amdgcn_s_setprio(1);
    acc[0][0] = __builtin_amdgcn_mfma_f32_32x32x16_f16(Af[cur][0], Bf[cur][0], acc[0][0], 0, 0, 0);
    acc[0][1] = __builtin_amdgcn_mfma_f32_32x32x16_f16(Af[cur][0], Bf[cur][1], acc[0][1], 0, 0, 0);
    acc[0][2] = __builtin_amdgcn_mfma_f32_32x32x16_f16(Af[cur][0], Bf[cur][2], acc[0][2], 0, 0, 0);
    acc[0][3] = __builtin_amdgcn_mfma_f32_32x32x16_f16(Af[cur][0], Bf[cur][3], acc[0][3], 0, 0, 0);
    acc[1][0] = __builtin_amdgcn_mfma_f32_32x32x16_f16(Af[cur][1], Bf[cur][0], acc[1][0], 0, 0, 0);
    acc[1][1] = __builtin_amdgcn_mfma_f32_32x32x16_f16(Af[cur][1], Bf[cur][1], acc[1][1], 0, 0, 0);
    acc[1][2] = __builtin_amdgcn_mfma_f32_32x32x16_f16(Af[cur][1], Bf[cur][2], acc[1][2], 0, 0, 0);
    acc[1][3] = __builtin_amdgcn_mfma_f32_32x32x16_f16(Af[cur][1], Bf[cur][3], acc[1][3], 0, 0, 0);
    __builtin_amdgcn_s_setprio(0);

    // 5+6. drain own stage(ks+2) (issued ~400cyc ago) then barrier -> visible to all
    if (ks + 2 < NK)
      asm volatile("s_waitcnt vmcnt(0)" ::: "memory");
    __builtin_amdgcn_s_barrier();
    asm volatile("" ::: "memory");
  }
  // all waves past final barrier + lgkmcnt(0) => in-place act write safe

#pragma unroll
  for (int nt = 0; nt < 2; ++nt)
#pragma unroll
    for (int mt = 0; mt < 4; ++mt)
#pragma unroll
      for (int g = 0; g < 4; ++g) {
        f16x4v o;
        o[0] = (f16)fmaxf(acc[nt][mt][4 * g + 0], 0.f);
        o[1] = (f16)fmaxf(acc[nt][mt][4 * g + 1], 0.f);
        o[2] = (f16)fmaxf(acc[nt][mt][4 * g + 2], 0.f);
        o[3] = (f16)fmaxf(acc[nt][mt][4 * g + 3], 0.f);
        *(f16x4v*)(act + (size_t)(wm * 128 + mt * 32 + lo) * AST +
                   wn * 64 + nt * 32 + 8 * g + 4 * hi) = o;
      }
}

template<bool USE_FT>
__global__ __launch_bounds__(512, 2) void inr2d_mfma(
    const float* __restrict__ feat, const f16* __restrict__ ft,
    const float* __restrict__ b0, const float* __restrict__ b1,
    const float* __restrict__ b2, const float* __restrict__ b3,
    const f16* __restrict__ ws, float* __restrict__ out)
{
  __shared__ f16 act[MROWS][AST];      // 132 KB
  __shared__ f16 wlds[3 * 4096];       // 24 KB W staging ring (3 x 8 KB)
  __shared__ float area_s[MROWS];      // 1 KB
  __shared__ f16 pred_s[MROWS][4];     // 2 KB   -> total 162,816 B

  const int t = threadIdx.x;
  // XCD-chunked swizzle (4096 % 8 == 0 -> bijective)
  const int blk = ((blockIdx.x & 7) << 9) | (blockIdx.x >> 3);

  // ---------- phase 0: build 256 input rows (64 px x 4 ensembles), f16 ----------
  {
    const int r = t >> 1, sub = t & 1;     // 2 threads per row, 32 ch each
    const int pix = r >> 2, e = r & 3;
    const int gp = blk * PIXB + pix;
    const int b = gp >> 16, rem = gp & 65535;
    const int oy = rem >> 8, ox = rem & 255;

    const float cy = (2.0f * oy + 1.0f) / (float)TH - 1.0f;
    const float cx = (2.0f * ox + 1.0f) / (float)TW - 1.0f;
    const float vx = (e & 2) ? 1.0f : -1.0f;
    const float vy = (e & 1) ? 1.0f : -1.0f;
    const float rr = 1.0f / (float)NH;

    float c0 = fminf(fmaxf(cy + vx * rr + 1e-6f, -1.0f + 1e-6f), 1.0f - 1e-6f);
    float c1 = fminf(fmaxf(cx + vy * rr + 1e-6f, -1.0f + 1e-6f), 1.0f - 1e-6f);

    const float ix = (c1 + 1.0f) * 0.5f * (float)(NW - 1);
    const float iy = (c0 + 1.0f) * 0.5f * (float)(NH - 1);
    const float x0f = floorf(ix), y0f = floorf(iy);
    int x0 = (int)x0f; x0 = max(0, min(x0, NW - 1));
    int x1 = min(x0 + 1, NW - 1);
    int y0 = (int)y0f; y0 = max(0, min(y0, NH - 1));
    int y1 = min(y0 + 1, NH - 1);
    const float wx1 = ix - x0f, wx0 = 1.0f - wx1;
    const float wy1 = iy - y0f, wy0 = 1.0f - wy1;
    const float w00 = wy0 * wx0, w01 = wy0 * wx1, w10 = wy1 * wx0, w11 = wy1 * wx1;

    if (USE_FT) {
      const f16* fb = ft + (size_t)b * (NH * NW * 64);
      const f16* r00 = fb + (size_t)(y0 * NW + x0) * 64 + sub * 32;
      const f16* r01 = fb + (size_t)(y0 * NW + x1) * 64 + sub * 32;
      const f16* r10 = fb + (size_t)(y1 * NW + x0) * 64 + sub * 32;
      const f16* r11 = fb + (size_t)(y1 * NW + x1) * 64 + sub * 32;
#pragma unroll
      for (int h = 0; h < 4; ++h) {
        const f16x8 a00 = *(const f16x8*)(r00 + h * 8);
        const f16x8 a01 = *(const f16x8*)(r01 + h * 8);
        const f16x8 a10 = *(const f16x8*)(r10 + h * 8);
        const f16x8 a11 = *(const f16x8*)(r11 + h * 8);
#pragma unroll
        for (int i = 0; i < 8; ++i) {
          const float v = w00 * (float)a00[i] + w01 * (float)a01[i] +
                          w10 * (float)a10[i] + w11 * (float)a11[i];
          act[r][sub * 32 + h * 8 + i] = (f16)v;
        }
      }
    } else {
      const float* fb = feat + (size_t)b * 64 * NH * NW;
      const int i00 = y0 * NW + x0, i01 = y0 * NW + x1;
      const int i10 = y1 * NW + x0, i11 = y1 * NW + x1;
#pragma unroll
      for (int i = 0; i < 32; ++i) {
        const int c = sub * 32 + i;
        const float* fc = fb + (size_t)c * (NH * NW);
        const float v = w00 * fc[i00] + w01 * fc[i01] + w10 * fc[i10] + w11 * fc[i11];
        act[r][c] = (f16)v;
      }
    }
    if (sub == 0) {
      const float qy = -1.0f + 1.0f / NH + (2.0f / NH) * (wy0 * (float)y0 + wy1 * (float)y1);
      const float qx = -1.0f + 1.0f / NW + (2.0f / NW) * (wx0 * (float)x0 + wx1 * (float)x1);
      const float rely = (cy - qy) * (float)NH;
      const float relx = (cx - qx) * (float)NW;
      act[r][64] = (f16)rely;
      act[r][65] = (f16)relx;
      if (USE_FT) {
        const f16* py = ws + OFF_PE + (size_t)oy * 8;
        const f16* px = ws + OFF_PE + 2048 + (size_t)ox * 8;
#pragma unroll
        for (int j = 0; j < 8; ++j) { act[r][66 + j] = py[j]; act[r][74 + j] = px[j]; }
      } else {
#pragma unroll
        for (int ll = 0; ll < 4; ++ll) {
          const float f = (float)(1 << ll) * (float)M_PI;
          act[r][66 + ll] = (f16)sinf(cy * f);
          act[r][70 + ll] = (f16)cosf(cy * f);
          act[r][74 + ll] = (f16)sinf(cx * f);
          act[r][78 + ll] = (f16)cosf(cx * f);
        }
      }
      act[r][82] = (f16)1.0f;   // rel_cell: 2/256*128 = 1.0
      act[r][83] = (f16)1.0f;
#pragma unroll
      for (int z = 84; z < K0; ++z) act[r][z] = (f16)0.f;  // K-pad
      area_s[r] = fabsf(rely * relx) + 1e-9f;
    }
  }
  __syncthreads();

  const int w = t >> 6, l = t & 63;
  const int wm = w >> 2, wn = w & 3;   // wave tile: rows wm*128.., cols wn*64..

  dense_layer<K0 >(ws,          b0, &act[0][0], wlds, wm, wn, l, t);
  __syncthreads();
  dense_layer<256>(ws + OFF_W1, b1, &act[0][0], wlds, wm, wn, l, t);
  __syncthreads();
  dense_layer<256>(ws + OFF_W2, b2, &act[0][0], wlds, wm, wn, l, t);
  __syncthreads();

  // ---------- layer 3: 256 -> 3 (wave w handles rows w*32 .. w*32+31) ----------
  {
    const int nl = l & 15, kq = l >> 4;
    const f16* Abase = ws + OFF_W3 + nl * 256 + kq * 8;
#pragma unroll
    for (int p = 0; p < 2; ++p) {
      const f16* Bbase2 = &act[w * 32 + p * 16 + nl][0] + kq * 8;
      f32x4 acc = {0.f, 0.f, 0.f, 0.f};
#pragma unroll
      for (int ks = 0; ks < 8; ++ks) {
        f16x8 a = *(const f16x8*)(Abase + ks * 32);
        f16x8 b = *(const f16x8*)(Bbase2 + ks * 32);
        acc = __builtin_amdgcn_mfma_f32_16x16x32_f16(a, b, acc, 0, 0, 0);
      }
      if (l < 16) {
        f16x4v pr;
        pr[0] = (f16)(acc[0] + b3[0]); pr[1] = (f16)(acc[1] + b3[1]);
        pr[2] = (f16)(acc[2] + b3[2]); pr[3] = (f16)0.f;
        *(f16x4v*)(&pred_s[w * 32 + p * 16 + l][0]) = pr;
      }
    }
  }
  __syncthreads();

  // ---------- ensemble combine: pred_e weighted by area[3-e]/tot ----------
  if (t < PIXB * 3) {
    const int pix = t / 3, o = t - pix * 3;
    const int gp = blk * PIXB + pix;
    const int b = gp >> 16, rem = gp & 65535;
    const int oy = rem >> 8, ox = rem & 255;
    const int r0 = pix * 4;
    const float a0 = area_s[r0], a1 = area_s[r0 + 1], a2 = area_s[r0 + 2], a3 = area_s[r0 + 3];
    const float tot = a0 + a1 + a2 + a3;
    const float v = (float)pred_s[r0][o] * a3 + (float)pred_s[r0 + 1][o] * a2 +
                    (float)pred_s[r0 + 2][o] * a1 + (float)pred_s[r0 + 3][o] * a0;
    out[(((size_t)b * 3 + o) << 16) + (oy << 8) + ox] = v / tot;
  }
}

extern "C" void kernel_launch(void* const* d_in, const int* in_sizes, int n_in,
                              void* d_out, int out_size, void* d_ws, size_t ws_size,
                              hipStream_t stream) {
  const float* feat = (const float*)d_in[0];
  const float* w0 = (const float*)d_in[1];
  const float* b0 = (const float*)d_in[2];
  const float* w1 = (const float*)d_in[3];
  const float* b1 = (const float*)d_in[4];
  const float* w2 = (const float*)d_in[5];
  const float* b2 = (const float*)d_in[6];
  const float* w3 = (const float*)d_in[7];
  const float* b3 = (const float*)d_in[8];
  float* out = (float*)d_out;
  f16* ws = (f16*)d_ws;

  cvt_weights<<<(WS_W_ELEMS + 255) / 256, 256, 0, stream>>>(w0, w1, w2, w3, ws);

  const int blocks = (NB * TH * TW) / PIXB;  // 4096
  const bool use_ft = ws_size >= (size_t)(WS_W_ELEMS + FT_ELEMS) * sizeof(f16);
  if (use_ft) {
    f16* ft = ws + WS_W_ELEMS;
    transpose_feat<<<NB * NH * (NW / 64), 256, 0, stream>>>(feat, ft);
    inr2d_mfma<true><<<blocks, 512, 0, stream>>>(feat, ft, b0, b1, b2, b3, ws, out);
  } else {
    inr2d_mfma<false><<<blocks, 512, 0, stream>>>(feat, nullptr, b0, b1, b2, b3, ws, out);
  }
}